// Round 1
// baseline (2357.118 us; speedup 1.0000x reference)
//
#include <hip/hip_runtime.h>
#include <hip/hip_bf16.h>
#include <math.h>

#define B_ 64
#define C_ 512
#define N_ 1024
#define D_ 128
#define K_ 8

typedef __attribute__((ext_vector_type(8))) short bf16x8;  // 8 bf16 = 4 VGPRs
typedef __attribute__((ext_vector_type(4))) float f32x4;
typedef unsigned short ushort_t;

__device__ __forceinline__ unsigned short f2bs(float f) {
    union { __hip_bfloat16 h; unsigned short s; } u;
    u.h = __float2bfloat16(f);
    return u.s;
}
__device__ __forceinline__ float bs2f(unsigned short s) {
    union { unsigned int u; float f; } v;
    v.u = ((unsigned int)s) << 16;
    return v.f;
}
__device__ __forceinline__ float sigmoidf_(float x) { return 1.0f / (1.0f + expf(-x)); }
__device__ __forceinline__ float gelu_exact(float x) {
    return 0.5f * x * (1.0f + erff(x * 0.7071067811865476f));
}

// ---------------------------------------------------------------------------
// K0: weight prep (unchanged). WTih/WThh now unused by the fused kernel but
// kept to avoid touching proven code.
// ---------------------------------------------------------------------------
__global__ __launch_bounds__(256) void prep_weights(
    const float* __restrict__ Wp, const float* __restrict__ Wk,
    const float* __restrict__ Wv, const float* __restrict__ W_ih,
    const float* __restrict__ W_hh,
    ushort_t* __restrict__ WpT, ushort_t* __restrict__ WkT,
    ushort_t* __restrict__ WvT, float* __restrict__ WTih,
    float* __restrict__ WThh)
{
    int tid = blockIdx.x * 256 + threadIdx.x;   // grid 256*256 = 65536
    {
        int c = tid >> 7, d = tid & 127;        // coalesced read of Wp
        WpT[d * 512 + c] = f2bs(Wp[tid]);
    }
    if (tid < 16384) {
        int c = tid >> 7, d = tid & 127;
        WkT[d * 128 + c] = f2bs(Wk[tid]);
        WvT[d * 128 + c] = f2bs(Wv[tid]);
    }
    if (tid < 49152) {
        int j = tid >> 7, c = tid & 127;        // coalesced read of W_ih
        WTih[c * 384 + j] = W_ih[tid];
        WThh[c * 384 + j] = W_hh[tid];
    }
}

// ---------------------------------------------------------------------------
// K1: inputs = LN(x_flat @ Wp + bp)*g+b via MFMA bf16 (unchanged).
// ---------------------------------------------------------------------------
__global__ __launch_bounds__(256) void proj_ln_mfma(
    const float* __restrict__ x, const ushort_t* __restrict__ WpT,
    const float* __restrict__ bp, const float* __restrict__ g_in,
    const float* __restrict__ b_in, ushort_t* __restrict__ outb)
{
    __shared__ ushort_t Al[64 * 40];
    __shared__ ushort_t Bl[128 * 40];
    __shared__ float red[64][2][2];
    const int t = threadIdx.x;
    const int b = blockIdx.x >> 4;
    const int n0 = (blockIdx.x & 15) << 6;
    const int w = t >> 6, lane = t & 63;
    const int quad = lane >> 4, m = lane & 15;
    const int rowoff = (w >> 1) << 5;   // 0 / 32
    const int coloff = (w & 1) << 6;    // 0 / 64

    f32x4 acc[2][4];
#pragma unroll
    for (int r = 0; r < 2; ++r)
#pragma unroll
        for (int c = 0; c < 4; ++c) acc[r][c] = (f32x4){0.f, 0.f, 0.f, 0.f};

    const float* xb = x + (size_t)b * (C_ * N_);
    for (int c0 = 0; c0 < C_; c0 += 32) {
#pragma unroll
        for (int i = 0; i < 8; ++i) {
            int idx = t + (i << 8);
            int cc = idx >> 6, nn = idx & 63;
            Al[nn * 40 + cc] = f2bs(xb[(size_t)(c0 + cc) * N_ + n0 + nn]);
        }
#pragma unroll
        for (int i = 0; i < 2; ++i) {
            int idx = t + (i << 8);           // 0..511
            int d = idx >> 2, seg = idx & 3;  // 128 rows x 4 segs of 8
            *(bf16x8*)&Bl[d * 40 + seg * 8] =
                *(const bf16x8*)&WpT[d * 512 + c0 + seg * 8];
        }
        __syncthreads();
        bf16x8 af[2], bfr[4];
#pragma unroll
        for (int r = 0; r < 2; ++r)
            af[r] = *(const bf16x8*)&Al[(rowoff + 16 * r + m) * 40 + quad * 8];
#pragma unroll
        for (int c = 0; c < 4; ++c)
            bfr[c] = *(const bf16x8*)&Bl[(coloff + 16 * c + m) * 40 + quad * 8];
#pragma unroll
        for (int r = 0; r < 2; ++r)
#pragma unroll
            for (int c = 0; c < 4; ++c)
                acc[r][c] = __builtin_amdgcn_mfma_f32_16x16x32_bf16(af[r], bfr[c], acc[r][c], 0, 0, 0);
        __syncthreads();
    }
    float gv[4], bv[4], bpv[4];
#pragma unroll
    for (int c = 0; c < 4; ++c) {
        int col = coloff + 16 * c + m;
        bpv[c] = bp[col]; gv[c] = g_in[col]; bv[c] = b_in[col];
    }
#pragma unroll
    for (int r = 0; r < 2; ++r)
#pragma unroll
        for (int c = 0; c < 4; ++c)
#pragma unroll
            for (int g = 0; g < 4; ++g) acc[r][c][g] += bpv[c];

#pragma unroll
    for (int r = 0; r < 2; ++r) {
#pragma unroll
        for (int g = 0; g < 4; ++g) {
            float s = 0.f, s2 = 0.f;
#pragma unroll
            for (int c = 0; c < 4; ++c) { float v = acc[r][c][g]; s += v; s2 += v * v; }
#pragma unroll
            for (int off = 1; off < 16; off <<= 1) {
                s += __shfl_xor(s, off, 64);
                s2 += __shfl_xor(s2, off, 64);
            }
            if (m == 0) {
                int row = rowoff + 16 * r + quad * 4 + g;
                red[row][w & 1][0] = s;
                red[row][w & 1][1] = s2;
            }
        }
    }
    __syncthreads();
#pragma unroll
    for (int r = 0; r < 2; ++r) {
#pragma unroll
        for (int g = 0; g < 4; ++g) {
            int row = rowoff + 16 * r + quad * 4 + g;
            float s = red[row][0][0] + red[row][1][0];
            float s2 = red[row][0][1] + red[row][1][1];
            float mean = s * (1.f / 128.f);
            float var = s2 * (1.f / 128.f) - mean * mean;
            float rs = rsqrtf(var + 1e-5f);
            size_t base = ((size_t)b * N_ + n0 + row) * D_;
#pragma unroll
            for (int c = 0; c < 4; ++c) {
                int col = coloff + 16 * c + m;
                float v = (acc[r][c][g] - mean) * rs * gv[c] + bv[c];
                outb[base + col] = f2bs(v);
            }
        }
    }
}

// ---------------------------------------------------------------------------
// K2: k/v = A@Wk/Wv + bias (unchanged).
// ---------------------------------------------------------------------------
__global__ __launch_bounds__(256) void kv_mfma(
    const ushort_t* __restrict__ A,
    const ushort_t* __restrict__ WkT, const float* __restrict__ bk,
    const ushort_t* __restrict__ WvT, const float* __restrict__ bv,
    ushort_t* __restrict__ kout, ushort_t* __restrict__ vout)
{
    __shared__ ushort_t Al[64 * 40];
    __shared__ ushort_t Bk[128 * 40];
    __shared__ ushort_t Bv[128 * 40];
    const int t = threadIdx.x;
    const int row0 = blockIdx.x << 6;
    const int w = t >> 6, lane = t & 63;
    const int quad = lane >> 4, m = lane & 15;
    const int is_v = w >> 1;
    const int rowoff = (w & 1) << 5;

    f32x4 acc[2][8];
#pragma unroll
    for (int r = 0; r < 2; ++r)
#pragma unroll
        for (int c = 0; c < 8; ++c) acc[r][c] = (f32x4){0.f, 0.f, 0.f, 0.f};

    for (int c0 = 0; c0 < D_; c0 += 32) {
#pragma unroll
        for (int i = 0; i < 2; ++i) {
            int idx = t + (i << 8);
            int rr = idx >> 3, cc4 = (idx & 7) << 2;
            *(ushort4*)&Al[rr * 40 + cc4] =
                *(const ushort4*)&A[(size_t)(row0 + rr) * D_ + c0 + cc4];
        }
#pragma unroll
        for (int i = 0; i < 2; ++i) {
            int idx = t + (i << 8);
            int d = idx >> 2, seg = idx & 3;
            *(bf16x8*)&Bk[d * 40 + seg * 8] =
                *(const bf16x8*)&WkT[d * 128 + c0 + seg * 8];
            *(bf16x8*)&Bv[d * 40 + seg * 8] =
                *(const bf16x8*)&WvT[d * 128 + c0 + seg * 8];
        }
        __syncthreads();
        const ushort_t* Bsrc = is_v ? Bv : Bk;
        bf16x8 af[2], bfr[8];
#pragma unroll
        for (int r = 0; r < 2; ++r)
            af[r] = *(const bf16x8*)&Al[(rowoff + 16 * r + m) * 40 + quad * 8];
#pragma unroll
        for (int c = 0; c < 8; ++c)
            bfr[c] = *(const bf16x8*)&Bsrc[(16 * c + m) * 40 + quad * 8];
#pragma unroll
        for (int r = 0; r < 2; ++r)
#pragma unroll
            for (int c = 0; c < 8; ++c)
                acc[r][c] = __builtin_amdgcn_mfma_f32_16x16x32_bf16(af[r], bfr[c], acc[r][c], 0, 0, 0);
        __syncthreads();
    }
    const float* bias = is_v ? bv : bk;
    ushort_t* dst = is_v ? vout : kout;
    float bval[8];
#pragma unroll
    for (int c = 0; c < 8; ++c) bval[c] = bias[16 * c + m];
#pragma unroll
    for (int r = 0; r < 2; ++r) {
#pragma unroll
        for (int g = 0; g < 4; ++g) {
            int row = rowoff + 16 * r + quad * 4 + g;
            size_t base = (size_t)(row0 + row) * D_;
#pragma unroll
            for (int c = 0; c < 8; ++c)
                dst[base + 16 * c + m] = f2bs(acc[r][c][g] + bval[c]);
        }
    }
}

// ---------------------------------------------------------------------------
// K3 (NEW): fully fused slot-attention loop. One block per batch element.
// 64 blocks x 1024 threads (16 waves). All iteration state lives in LDS:
//   slots, q, attn[8x1024], upd, GRU/MLP temps. k/v streamed from L2.
// Replaces slots_init + 3x{q_ln, attn, updates, gru_mlp} = 13 dispatches.
// Precision path identical to the multi-kernel version (f32 everywhere,
// bf16 only for k/v operands).
// ---------------------------------------------------------------------------
__global__ __launch_bounds__(1024) void fused_slots(
    const ushort_t* __restrict__ kb, const ushort_t* __restrict__ vb,
    const float* __restrict__ noise, const float* __restrict__ mu,
    const float* __restrict__ lsig,
    const float* __restrict__ g_slots, const float* __restrict__ b_slots,
    const float* __restrict__ Wq, const float* __restrict__ bq,
    const float* __restrict__ W_ih, const float* __restrict__ W_hh,
    const float* __restrict__ b_ih, const float* __restrict__ b_hh,
    const float* __restrict__ W1, const float* __restrict__ b1,
    const float* __restrict__ W2, const float* __restrict__ b2,
    const float* __restrict__ g_mlp, const float* __restrict__ b_mlp,
    float* __restrict__ out_slots, float* __restrict__ out_attn)
{
    __shared__ float sl[8][132];      // slots
    __shared__ float u_[8][132];      // ln(slots) -> upd -> ln_mlp temp
    __shared__ float sn_[8][132];     // GRU output
    __shared__ float q_[8][132];
    __shared__ float attnT[8][1032];  // logits -> softmax attn
    __shared__ __align__(16) char scratch[69632]; // kvt[256][136] bf16  U  red[16][8][132] f32
    __shared__ float hm_[8][260];     // MLP hidden
    __shared__ float red2[16][8];     // per-wave S partials
    __shared__ float S_[8];
    __shared__ float mrs_[8][2];

    ushort_t* kvt = (ushort_t*)scratch;
    float* red = (float*)scratch;

    const int t = threadIdx.x;
    const int b = blockIdx.x;
    const int wv = t >> 6, lane = t & 63;
    const float SCALE = 0.08838834764831845f;

    // slots init
    {
        int k = t >> 7, d = t & 127;
        int kd = k * 128 + d;
        sl[k][d] = mu[kd] + expf(lsig[kd]) * noise[b * 1024 + kd];
    }
    __syncthreads();

    for (int it = 0; it < 3; ++it) {
        const int last = (it == 2);

        // ---- A1: LN stats over slots (waves 0-7) + zero attnT (waves 8-15)
        if (wv < 8) {
            float v0 = sl[wv][lane], v1 = sl[wv][lane + 64];
            float s = v0 + v1, s2 = v0 * v0 + v1 * v1;
            for (int off = 32; off > 0; off >>= 1) {
                s += __shfl_down(s, off, 64);
                s2 += __shfl_down(s2, off, 64);
            }
            if (lane == 0) {
                float mean = s * (1.f / 128.f);
                float var = s2 * (1.f / 128.f) - mean * mean;
                mrs_[wv][0] = mean; mrs_[wv][1] = rsqrtf(var + 1e-5f);
            }
        } else {
            float* az = &attnT[0][0];
            for (int i = t - 512; i < 8 * 1032; i += 512) az[i] = 0.f;
        }
        __syncthreads();

        // ---- A2: u_ = LN(slots)*g+b
        {
            int k = t >> 7, d = t & 127;
            u_[k][d] = (sl[k][d] - mrs_[k][0]) * mrs_[k][1] * g_slots[d] + b_slots[d];
        }
        __syncthreads();

        // ---- A3: q = u_ @ Wq + bq
        {
            int k = t >> 7, d = t & 127;
            float a = bq[d];
            for (int c0 = 0; c0 < 128; c0 += 4) {
                f32x4 u4 = *(const f32x4*)&u_[k][c0];
                a = fmaf(u4[0], Wq[(size_t)(c0    ) * 128 + d], a);
                a = fmaf(u4[1], Wq[(size_t)(c0 + 1) * 128 + d], a);
                a = fmaf(u4[2], Wq[(size_t)(c0 + 2) * 128 + d], a);
                a = fmaf(u4[3], Wq[(size_t)(c0 + 3) * 128 + d], a);
            }
            q_[k][d] = a;
        }
        __syncthreads();

        // ---- B: logits (k from global/L2, q broadcast from LDS)
        // thread: rows {g, g+256, g+512, g+768}, c-range [32*cq, 32*cq+32)
        {
            const int g = t & 255, cq = t >> 8;
            float acc[4][8];
#pragma unroll
            for (int r = 0; r < 4; ++r)
#pragma unroll
                for (int k = 0; k < 8; ++k) acc[r][k] = 0.f;
#pragma unroll
            for (int ch = 0; ch < 2; ++ch) {
                const int cbase = cq * 32 + ch * 16;
                bf16x8 kr[4][2];
#pragma unroll
                for (int r = 0; r < 4; ++r) {
                    const ushort_t* src = &kb[((size_t)b * N_ + g + 256 * r) * D_ + cbase];
                    kr[r][0] = *(const bf16x8*)src;
                    kr[r][1] = *(const bf16x8*)(src + 8);
                }
#pragma unroll
                for (int c4 = 0; c4 < 4; ++c4) {
                    float kf[4][4];
#pragma unroll
                    for (int r = 0; r < 4; ++r)
#pragma unroll
                        for (int j = 0; j < 4; ++j)
                            kf[r][j] = bs2f((ushort_t)kr[r][c4 >> 1][(c4 & 1) * 4 + j]);
#pragma unroll
                    for (int k = 0; k < 8; ++k) {
                        f32x4 q4 = *(const f32x4*)&q_[k][cbase + c4 * 4];
#pragma unroll
                        for (int r = 0; r < 4; ++r) {
                            acc[r][k] = fmaf(q4[0], kf[r][0], acc[r][k]);
                            acc[r][k] = fmaf(q4[1], kf[r][1], acc[r][k]);
                            acc[r][k] = fmaf(q4[2], kf[r][2], acc[r][k]);
                            acc[r][k] = fmaf(q4[3], kf[r][3], acc[r][k]);
                        }
                    }
                }
            }
#pragma unroll
            for (int r = 0; r < 4; ++r)
#pragma unroll
                for (int k = 0; k < 8; ++k)
                    atomicAdd(&attnT[k][g + 256 * r], acc[r][k]);
        }
        __syncthreads();

        // ---- softmax over k (per n) + S[k] = sum_n attn
        {
            const int n = t;
            float l[8];
#pragma unroll
            for (int k = 0; k < 8; ++k) l[k] = attnT[k][n] * SCALE;
            float mx = l[0];
#pragma unroll
            for (int k = 1; k < 8; ++k) mx = fmaxf(mx, l[k]);
            float e[8], ssum = 0.f;
#pragma unroll
            for (int k = 0; k < 8; ++k) { e[k] = expf(l[k] - mx); ssum += e[k]; }
            float inv = 1.f / ssum;
            float ps[8];
#pragma unroll
            for (int k = 0; k < 8; ++k) {
                ps[k] = e[k] * inv;
                attnT[k][n] = ps[k];
                if (last) out_attn[((size_t)b * K_ + k) * N_ + n] = ps[k];
            }
#pragma unroll
            for (int k = 0; k < 8; ++k) {
                float v = ps[k];
                for (int off = 32; off > 0; off >>= 1) v += __shfl_down(v, off, 64);
                if (lane == 0) red2[wv][k] = v;
            }
        }
        __syncthreads();
        if (t < 8) {
            float ss = 0.f;
#pragma unroll
            for (int w = 0; w < 16; ++w) ss += red2[w][t];
            S_[t] = ss;
        }
        // (S_ consumed after more barriers below)

        // ---- C: updates = attn_norm @ v  (v staged in LDS chunks of 256 rows)
        {
            float acc[8][4];
#pragma unroll
            for (int k = 0; k < 8; ++k)
#pragma unroll
                for (int j = 0; j < 4; ++j) acc[k][j] = 0.f;
            const int d4 = (t & 31) * 4, s = t >> 5;   // strip s: 8 n per chunk
            for (int chunk = 0; chunk < 4; ++chunk) {
                const int n0 = chunk * 256;
                __syncthreads();   // prev chunk compute done before overwrite
#pragma unroll
                for (int i = 0; i < 4; ++i) {
                    int idx = t + (i << 10);
                    int row = idx >> 4, u8 = (idx & 15) << 3;
                    *(bf16x8*)&kvt[row * 136 + u8] =
                        *(const bf16x8*)&vb[((size_t)b * N_ + n0 + row) * D_ + u8];
                }
                __syncthreads();
#pragma unroll
                for (int i2 = 0; i2 < 2; ++i2) {
                    const int nn = s * 8 + i2 * 4;
                    float vf[4][4];
#pragma unroll
                    for (int i = 0; i < 4; ++i) {
                        ushort4 v4 = *(const ushort4*)&kvt[(nn + i) * 136 + d4];
                        vf[i][0] = bs2f(v4.x); vf[i][1] = bs2f(v4.y);
                        vf[i][2] = bs2f(v4.z); vf[i][3] = bs2f(v4.w);
                    }
#pragma unroll
                    for (int k = 0; k < 8; ++k) {
                        f32x4 a4 = *(const f32x4*)&attnT[k][n0 + nn];
#pragma unroll
                        for (int i = 0; i < 4; ++i) {
                            acc[k][0] = fmaf(a4[i], vf[i][0], acc[k][0]);
                            acc[k][1] = fmaf(a4[i], vf[i][1], acc[k][1]);
                            acc[k][2] = fmaf(a4[i], vf[i][2], acc[k][2]);
                            acc[k][3] = fmaf(a4[i], vf[i][3], acc[k][3]);
                        }
                    }
                }
            }
            __syncthreads();   // all compute done; scratch becomes red[]
            // strip-pair reduce within wave, then cross-wave tree in LDS
#pragma unroll
            for (int k = 0; k < 8; ++k)
#pragma unroll
                for (int j = 0; j < 4; ++j)
                    acc[k][j] += __shfl_xor(acc[k][j], 32, 64);
            if (lane < 32) {
#pragma unroll
                for (int k = 0; k < 8; ++k)
#pragma unroll
                    for (int j = 0; j < 4; ++j)
                        red[(wv * 8 + k) * 132 + lane * 4 + j] = acc[k][j];
            }
            __syncthreads();
            {
                int k = t >> 7, d = t & 127;
                float ssum = 0.f;
#pragma unroll
                for (int w = 0; w < 16; ++w) ssum += red[(w * 8 + k) * 132 + d];
                u_[k][d] = ssum / (S_[k] + 1e-8f);   // attn_norm @ v, normalized
            }
        }
        __syncthreads();

        // ---- D: GRU (PyTorch gate order r,z,n). u_ = input, sl = hidden.
        {
            const int k = t >> 7, j = t & 127;
            float ax0 = 0.f, ax1 = 0.f, ax2 = 0.f;
            float ah0 = 0.f, ah1 = 0.f, ah2 = 0.f;
            for (int c0 = 0; c0 < 128; c0 += 16) {
                f32x4 u4[4], h4[4];
#pragma unroll
                for (int qi = 0; qi < 4; ++qi) {
                    u4[qi] = *(const f32x4*)&u_[k][c0 + qi * 4];
                    h4[qi] = *(const f32x4*)&sl[k][c0 + qi * 4];
                }
                const float* wih = &W_ih[(size_t)j * 128 + c0];
                const float* whh = &W_hh[(size_t)j * 128 + c0];
#pragma unroll
                for (int gi = 0; gi < 3; ++gi) {
                    const float* wr = wih + (size_t)gi * 16384;
                    float sx = 0.f;
#pragma unroll
                    for (int qi = 0; qi < 4; ++qi) {
                        f32x4 w4 = *(const f32x4*)(wr + qi * 4);
                        sx += u4[qi][0] * w4[0] + u4[qi][1] * w4[1]
                            + u4[qi][2] * w4[2] + u4[qi][3] * w4[3];
                    }
                    if (gi == 0) ax0 += sx; else if (gi == 1) ax1 += sx; else ax2 += sx;
                }
#pragma unroll
                for (int gi = 0; gi < 3; ++gi) {
                    const float* wr = whh + (size_t)gi * 16384;
                    float sh = 0.f;
#pragma unroll
                    for (int qi = 0; qi < 4; ++qi) {
                        f32x4 w4 = *(const f32x4*)(wr + qi * 4);
                        sh += h4[qi][0] * w4[0] + h4[qi][1] * w4[1]
                            + h4[qi][2] * w4[2] + h4[qi][3] * w4[3];
                    }
                    if (gi == 0) ah0 += sh; else if (gi == 1) ah1 += sh; else ah2 += sh;
                }
            }
            float r = sigmoidf_(ax0 + b_ih[j] + ah0 + b_hh[j]);
            float z = sigmoidf_(ax1 + b_ih[128 + j] + ah1 + b_hh[128 + j]);
            float nn = tanhf(ax2 + b_ih[256 + j] + r * (ah2 + b_hh[256 + j]));
            sn_[k][j] = (1.f - z) * nn + z * sl[k][j];
        }
        __syncthreads();

        // ---- LN(sn_) for MLP
        if (wv < 8) {
            float v0 = sn_[wv][lane], v1 = sn_[wv][lane + 64];
            float s = v0 + v1, s2 = v0 * v0 + v1 * v1;
            for (int off = 32; off > 0; off >>= 1) {
                s += __shfl_down(s, off, 64);
                s2 += __shfl_down(s2, off, 64);
            }
            if (lane == 0) {
                float mean = s * (1.f / 128.f);
                float var = s2 * (1.f / 128.f) - mean * mean;
                mrs_[wv][0] = mean; mrs_[wv][1] = rsqrtf(var + 1e-5f);
            }
        }
        __syncthreads();
        {
            int k = t >> 7, d = t & 127;
            u_[k][d] = (sn_[k][d] - mrs_[k][0]) * mrs_[k][1] * g_mlp[d] + b_mlp[d];
        }
        __syncthreads();

        // ---- MLP1: hm = gelu(u_ @ W1 + b1)   (W1 is [128][256], lanes coalesce on j)
        {
            const int k = t >> 7, j = t & 127;
            float a0 = 0.f, a1 = 0.f;
            for (int c0 = 0; c0 < 128; c0 += 4) {
                f32x4 t4 = *(const f32x4*)&u_[k][c0];
#pragma unroll
                for (int e = 0; e < 4; ++e) {
                    a0 = fmaf(t4[e], W1[(size_t)(c0 + e) * 256 + j], a0);
                    a1 = fmaf(t4[e], W1[(size_t)(c0 + e) * 256 + j + 128], a1);
                }
            }
            hm_[k][j] = gelu_exact(a0 + b1[j]);
            hm_[k][j + 128] = gelu_exact(a1 + b1[j + 128]);
        }
        __syncthreads();

        // ---- MLP2 + residual: slots = sn_ + hm @ W2 + b2
        {
            const int k = t >> 7, d = t & 127;
            float a = sn_[k][d] + b2[d];
            for (int j0 = 0; j0 < 256; j0 += 4) {
                f32x4 h4 = *(const f32x4*)&hm_[k][j0];
#pragma unroll
                for (int e = 0; e < 4; ++e)
                    a = fmaf(h4[e], W2[(size_t)(j0 + e) * 128 + d], a);
            }
            sl[k][d] = a;
            if (last) out_slots[((size_t)b * K_ + k) * D_ + d] = a;
        }
        __syncthreads();
    }
}

// ---------------------------------------------------------------------------
extern "C" void kernel_launch(void* const* d_in, const int* in_sizes, int n_in,
                              void* d_out, int out_size, void* d_ws, size_t ws_size,
                              hipStream_t stream) {
    const float* x       = (const float*)d_in[0];
    const float* noise   = (const float*)d_in[1];
    const float* slot_mu = (const float*)d_in[2];
    const float* slot_ls = (const float*)d_in[3];
    const float* Wp      = (const float*)d_in[4];
    const float* bp      = (const float*)d_in[5];
    const float* g_in    = (const float*)d_in[6];
    const float* b_in    = (const float*)d_in[7];
    const float* Wq      = (const float*)d_in[8];
    const float* bq      = (const float*)d_in[9];
    const float* Wk      = (const float*)d_in[10];
    const float* bk      = (const float*)d_in[11];
    const float* Wv      = (const float*)d_in[12];
    const float* bv      = (const float*)d_in[13];
    const float* W_ih    = (const float*)d_in[14];
    const float* W_hh    = (const float*)d_in[15];
    const float* b_ih    = (const float*)d_in[16];
    const float* b_hh    = (const float*)d_in[17];
    const float* W1      = (const float*)d_in[18];
    const float* b1      = (const float*)d_in[19];
    const float* W2      = (const float*)d_in[20];
    const float* b2      = (const float*)d_in[21];
    const float* g_slots = (const float*)d_in[22];
    const float* b_slots = (const float*)d_in[23];
    const float* g_mlp   = (const float*)d_in[24];
    const float* b_mlp   = (const float*)d_in[25];

    float* out_slots = (float*)d_out;            // [64,8,128] fp32
    float* out_attn  = (float*)d_out + 65536;    // [64,8,1024] fp32

    // workspace layout (float units) — unchanged offsets
    float* wsf = (float*)d_ws;
    ushort_t* inputsb = (ushort_t*)wsf;                    // 65536x128 bf16
    ushort_t* kb = (ushort_t*)(wsf + 4194304);             // 65536x128 bf16
    ushort_t* vb = (ushort_t*)(wsf + 8388608);             // 65536x128 bf16
    ushort_t* WpT = (ushort_t*)(wsf + 13304320);  // 128x512 bf16
    ushort_t* WkT = (ushort_t*)(wsf + 13337088);  // 128x128 bf16
    ushort_t* WvT = (ushort_t*)(wsf + 13345280);  // 128x128 bf16
    float* WTih = wsf + 13353472;    // 128x384 fp32 (unused by fused kernel)
    float* WThh = wsf + 13402624;    // 128x384 fp32 (unused by fused kernel)

    prep_weights<<<dim3(256), dim3(256), 0, stream>>>(
        Wp, Wk, Wv, W_ih, W_hh, WpT, WkT, WvT, WTih, WThh);
    proj_ln_mfma<<<dim3(1024), dim3(256), 0, stream>>>(x, WpT, bp, g_in, b_in, inputsb);
    kv_mfma<<<dim3(1024), dim3(256), 0, stream>>>(inputsb, WkT, bk, WvT, bv, kb, vb);

    fused_slots<<<dim3(64), dim3(1024), 0, stream>>>(
        kb, vb, noise, slot_mu, slot_ls, g_slots, b_slots, Wq, bq,
        W_ih, W_hh, b_ih, b_hh, W1, b1, W2, b2, g_mlp, b_mlp,
        out_slots, out_attn);
}

// Round 3
// 1208.666 us; speedup vs baseline: 1.9502x; 1.9502x over previous
//
#include <hip/hip_runtime.h>
#include <hip/hip_bf16.h>
#include <math.h>

#define B_ 64
#define C_ 512
#define N_ 1024
#define D_ 128
#define K_ 8

typedef __attribute__((ext_vector_type(8))) short bf16x8;  // 8 bf16 = 4 VGPRs
typedef __attribute__((ext_vector_type(4))) float f32x4;
typedef unsigned short ushort_t;

__device__ __forceinline__ unsigned short f2bs(float f) {
    union { __hip_bfloat16 h; unsigned short s; } u;
    u.h = __float2bfloat16(f);
    return u.s;
}
__device__ __forceinline__ float bs2f(unsigned short s) {
    union { unsigned int u; float f; } v;
    v.u = ((unsigned int)s) << 16;
    return v.f;
}
__device__ __forceinline__ float sigmoidf_(float x) { return 1.0f / (1.0f + expf(-x)); }
__device__ __forceinline__ float gelu_exact(float x) {
    return 0.5f * x * (1.0f + erff(x * 0.7071067811865476f));
}

// ---------------------------------------------------------------------------
// K0: weight prep (unchanged, proven).
// ---------------------------------------------------------------------------
__global__ __launch_bounds__(256) void prep_weights(
    const float* __restrict__ Wp, const float* __restrict__ Wk,
    const float* __restrict__ Wv, const float* __restrict__ W_ih,
    const float* __restrict__ W_hh,
    ushort_t* __restrict__ WpT, ushort_t* __restrict__ WkT,
    ushort_t* __restrict__ WvT, float* __restrict__ WTih,
    float* __restrict__ WThh)
{
    int tid = blockIdx.x * 256 + threadIdx.x;   // grid 256*256 = 65536
    {
        int c = tid >> 7, d = tid & 127;        // coalesced read of Wp
        WpT[d * 512 + c] = f2bs(Wp[tid]);
    }
    if (tid < 16384) {
        int c = tid >> 7, d = tid & 127;
        WkT[d * 128 + c] = f2bs(Wk[tid]);
        WvT[d * 128 + c] = f2bs(Wv[tid]);
    }
    if (tid < 49152) {
        int j = tid >> 7, c = tid & 127;        // coalesced read of W_ih
        WTih[c * 384 + j] = W_ih[tid];
        WThh[c * 384 + j] = W_hh[tid];
    }
}

// ---------------------------------------------------------------------------
// K1: inputs = LN(x_flat @ Wp + bp)*g+b via MFMA bf16 (unchanged, proven).
// ---------------------------------------------------------------------------
__global__ __launch_bounds__(256) void proj_ln_mfma(
    const float* __restrict__ x, const ushort_t* __restrict__ WpT,
    const float* __restrict__ bp, const float* __restrict__ g_in,
    const float* __restrict__ b_in, ushort_t* __restrict__ outb)
{
    __shared__ ushort_t Al[64 * 40];
    __shared__ ushort_t Bl[128 * 40];
    __shared__ float red[64][2][2];
    const int t = threadIdx.x;
    const int b = blockIdx.x >> 4;
    const int n0 = (blockIdx.x & 15) << 6;
    const int w = t >> 6, lane = t & 63;
    const int quad = lane >> 4, m = lane & 15;
    const int rowoff = (w >> 1) << 5;   // 0 / 32
    const int coloff = (w & 1) << 6;    // 0 / 64

    f32x4 acc[2][4];
#pragma unroll
    for (int r = 0; r < 2; ++r)
#pragma unroll
        for (int c = 0; c < 4; ++c) acc[r][c] = (f32x4){0.f, 0.f, 0.f, 0.f};

    const float* xb = x + (size_t)b * (C_ * N_);
    for (int c0 = 0; c0 < C_; c0 += 32) {
#pragma unroll
        for (int i = 0; i < 8; ++i) {
            int idx = t + (i << 8);
            int cc = idx >> 6, nn = idx & 63;
            Al[nn * 40 + cc] = f2bs(xb[(size_t)(c0 + cc) * N_ + n0 + nn]);
        }
#pragma unroll
        for (int i = 0; i < 2; ++i) {
            int idx = t + (i << 8);           // 0..511
            int d = idx >> 2, seg = idx & 3;  // 128 rows x 4 segs of 8
            *(bf16x8*)&Bl[d * 40 + seg * 8] =
                *(const bf16x8*)&WpT[d * 512 + c0 + seg * 8];
        }
        __syncthreads();
        bf16x8 af[2], bfr[4];
#pragma unroll
        for (int r = 0; r < 2; ++r)
            af[r] = *(const bf16x8*)&Al[(rowoff + 16 * r + m) * 40 + quad * 8];
#pragma unroll
        for (int c = 0; c < 4; ++c)
            bfr[c] = *(const bf16x8*)&Bl[(coloff + 16 * c + m) * 40 + quad * 8];
#pragma unroll
        for (int r = 0; r < 2; ++r)
#pragma unroll
            for (int c = 0; c < 4; ++c)
                acc[r][c] = __builtin_amdgcn_mfma_f32_16x16x32_bf16(af[r], bfr[c], acc[r][c], 0, 0, 0);
        __syncthreads();
    }
    float gv[4], bv[4], bpv[4];
#pragma unroll
    for (int c = 0; c < 4; ++c) {
        int col = coloff + 16 * c + m;
        bpv[c] = bp[col]; gv[c] = g_in[col]; bv[c] = b_in[col];
    }
#pragma unroll
    for (int r = 0; r < 2; ++r)
#pragma unroll
        for (int c = 0; c < 4; ++c)
#pragma unroll
            for (int g = 0; g < 4; ++g) acc[r][c][g] += bpv[c];

#pragma unroll
    for (int r = 0; r < 2; ++r) {
#pragma unroll
        for (int g = 0; g < 4; ++g) {
            float s = 0.f, s2 = 0.f;
#pragma unroll
            for (int c = 0; c < 4; ++c) { float v = acc[r][c][g]; s += v; s2 += v * v; }
#pragma unroll
            for (int off = 1; off < 16; off <<= 1) {
                s += __shfl_xor(s, off, 64);
                s2 += __shfl_xor(s2, off, 64);
            }
            if (m == 0) {
                int row = rowoff + 16 * r + quad * 4 + g;
                red[row][w & 1][0] = s;
                red[row][w & 1][1] = s2;
            }
        }
    }
    __syncthreads();
#pragma unroll
    for (int r = 0; r < 2; ++r) {
#pragma unroll
        for (int g = 0; g < 4; ++g) {
            int row = rowoff + 16 * r + quad * 4 + g;
            float s = red[row][0][0] + red[row][1][0];
            float s2 = red[row][0][1] + red[row][1][1];
            float mean = s * (1.f / 128.f);
            float var = s2 * (1.f / 128.f) - mean * mean;
            float rs = rsqrtf(var + 1e-5f);
            size_t base = ((size_t)b * N_ + n0 + row) * D_;
#pragma unroll
            for (int c = 0; c < 4; ++c) {
                int col = coloff + 16 * c + m;
                float v = (acc[r][c][g] - mean) * rs * gv[c] + bv[c];
                outb[base + col] = f2bs(v);
            }
        }
    }
}

// ---------------------------------------------------------------------------
// K2: k/v = A@Wk/Wv + bias (unchanged, proven).
// ---------------------------------------------------------------------------
__global__ __launch_bounds__(256) void kv_mfma(
    const ushort_t* __restrict__ A,
    const ushort_t* __restrict__ WkT, const float* __restrict__ bk,
    const ushort_t* __restrict__ WvT, const float* __restrict__ bv,
    ushort_t* __restrict__ kout, ushort_t* __restrict__ vout)
{
    __shared__ ushort_t Al[64 * 40];
    __shared__ ushort_t Bk[128 * 40];
    __shared__ ushort_t Bv[128 * 40];
    const int t = threadIdx.x;
    const int row0 = blockIdx.x << 6;
    const int w = t >> 6, lane = t & 63;
    const int quad = lane >> 4, m = lane & 15;
    const int is_v = w >> 1;
    const int rowoff = (w & 1) << 5;

    f32x4 acc[2][8];
#pragma unroll
    for (int r = 0; r < 2; ++r)
#pragma unroll
        for (int c = 0; c < 8; ++c) acc[r][c] = (f32x4){0.f, 0.f, 0.f, 0.f};

    for (int c0 = 0; c0 < D_; c0 += 32) {
#pragma unroll
        for (int i = 0; i < 2; ++i) {
            int idx = t + (i << 8);
            int rr = idx >> 3, cc4 = (idx & 7) << 2;
            *(ushort4*)&Al[rr * 40 + cc4] =
                *(const ushort4*)&A[(size_t)(row0 + rr) * D_ + c0 + cc4];
        }
#pragma unroll
        for (int i = 0; i < 2; ++i) {
            int idx = t + (i << 8);
            int d = idx >> 2, seg = idx & 3;
            *(bf16x8*)&Bk[d * 40 + seg * 8] =
                *(const bf16x8*)&WkT[d * 128 + c0 + seg * 8];
            *(bf16x8*)&Bv[d * 40 + seg * 8] =
                *(const bf16x8*)&WvT[d * 128 + c0 + seg * 8];
        }
        __syncthreads();
        const ushort_t* Bsrc = is_v ? Bv : Bk;
        bf16x8 af[2], bfr[8];
#pragma unroll
        for (int r = 0; r < 2; ++r)
            af[r] = *(const bf16x8*)&Al[(rowoff + 16 * r + m) * 40 + quad * 8];
#pragma unroll
        for (int c = 0; c < 8; ++c)
            bfr[c] = *(const bf16x8*)&Bsrc[(16 * c + m) * 40 + quad * 8];
#pragma unroll
        for (int r = 0; r < 2; ++r)
#pragma unroll
            for (int c = 0; c < 8; ++c)
                acc[r][c] = __builtin_amdgcn_mfma_f32_16x16x32_bf16(af[r], bfr[c], acc[r][c], 0, 0, 0);
        __syncthreads();
    }
    const float* bias = is_v ? bv : bk;
    ushort_t* dst = is_v ? vout : kout;
    float bval[8];
#pragma unroll
    for (int c = 0; c < 8; ++c) bval[c] = bias[16 * c + m];
#pragma unroll
    for (int r = 0; r < 2; ++r) {
#pragma unroll
        for (int g = 0; g < 4; ++g) {
            int row = rowoff + 16 * r + quad * 4 + g;
            size_t base = (size_t)(row0 + row) * D_;
#pragma unroll
            for (int c = 0; c < 8; ++c)
                dst[base + 16 * c + m] = f2bs(acc[r][c][g] + bval[c]);
        }
    }
}

// ---------------------------------------------------------------------------
// K3: fused slot loop, v2.1. 64 blocks x 512 threads (8 waves).
// __launch_bounds__(512, 2) -> VGPR cap 256: all per-phase accumulator arrays
// stay in registers (R1 failure: 1024 thr -> 64 VGPR cap -> 1.5 GB scratch
// traffic). Logits atomic-free: each thread owns 4 n-rows x 4 k fully.
// v2.1: explicit __align__(16) on all vector-accessed LDS arrays (defensive;
// R2 bench died at container level, kernel audit found no hang/OOB path).
// ---------------------------------------------------------------------------
__global__ __launch_bounds__(512, 2) void fused_slots(
    const ushort_t* __restrict__ kb, const ushort_t* __restrict__ vb,
    const float* __restrict__ noise, const float* __restrict__ mu,
    const float* __restrict__ lsig,
    const float* __restrict__ g_slots, const float* __restrict__ b_slots,
    const float* __restrict__ Wq, const float* __restrict__ bq,
    const float* __restrict__ W_ih, const float* __restrict__ W_hh,
    const float* __restrict__ b_ih, const float* __restrict__ b_hh,
    const float* __restrict__ W1, const float* __restrict__ b1,
    const float* __restrict__ W2, const float* __restrict__ b2,
    const float* __restrict__ g_mlp, const float* __restrict__ b_mlp,
    float* __restrict__ out_slots, float* __restrict__ out_attn)
{
    __shared__ __align__(16) float sl[8][132];      // slots
    __shared__ __align__(16) float u_[8][132];      // ln(slots) -> upd -> ln_mlp temp
    __shared__ __align__(16) float sn_[8][132];     // GRU output
    __shared__ __align__(16) float q_[8][132];
    __shared__ __align__(16) float attnT[8][1032];  // logits -> softmax attn
    __shared__ __align__(16) char scratch[69632];   // kvt[256][136] bf16 U red[8][8][132] f32
    __shared__ __align__(16) float hm_[8][260];     // MLP hidden
    __shared__ float red2[8][8];      // per-wave S partials
    __shared__ float S_[8];
    __shared__ float mrs_[8][2];

    ushort_t* kvt = (ushort_t*)scratch;
    float* red = (float*)scratch;

    const int t = threadIdx.x;
    const int b = blockIdx.x;
    const int wv = t >> 6, lane = t & 63;
    const float SCALE = 0.08838834764831845f;

    // slots init
    for (int i = t; i < 1024; i += 512) {
        sl[i >> 7][i & 127] = mu[i] + expf(lsig[i]) * noise[b * 1024 + i];
    }
    __syncthreads();

    for (int it = 0; it < 3; ++it) {
        const int last = (it == 2);

        // ---- A1: LN stats over slots: wave wv handles slot-row wv
        {
            float v0 = sl[wv][lane], v1 = sl[wv][lane + 64];
            float s = v0 + v1, s2 = v0 * v0 + v1 * v1;
            for (int off = 32; off > 0; off >>= 1) {
                s += __shfl_down(s, off, 64);
                s2 += __shfl_down(s2, off, 64);
            }
            if (lane == 0) {
                float mean = s * (1.f / 128.f);
                float var = s2 * (1.f / 128.f) - mean * mean;
                mrs_[wv][0] = mean; mrs_[wv][1] = rsqrtf(var + 1e-5f);
            }
        }
        __syncthreads();

        // ---- A2: u_ = LN(slots)*g+b
        for (int i = t; i < 1024; i += 512) {
            int k = i >> 7, d = i & 127;
            u_[k][d] = (sl[k][d] - mrs_[k][0]) * mrs_[k][1] * g_slots[d] + b_slots[d];
        }
        __syncthreads();

        // ---- A3: q = u_ @ Wq + bq  (thread: d = t&127, slots kk and kk+4;
        //      one Wq element load serves both slots)
        {
            const int d = t & 127, kk = t >> 7;
            float a0 = bq[d], a1 = bq[d];
            for (int c0 = 0; c0 < 128; c0 += 4) {
                f32x4 u0 = *(const f32x4*)&u_[kk][c0];
                f32x4 u1 = *(const f32x4*)&u_[kk + 4][c0];
#pragma unroll
                for (int e = 0; e < 4; ++e) {
                    float w = Wq[(size_t)(c0 + e) * 128 + d];
                    a0 = fmaf(u0[e], w, a0);
                    a1 = fmaf(u1[e], w, a1);
                }
            }
            q_[kk][d] = a0;
            q_[kk + 4][d] = a1;
        }
        __syncthreads();

        // ---- B: logits. Thread (g = t&255, kq = t>>8) owns
        //      n in {g, g+256, g+512, g+768} x k in {4kq..4kq+3}: full 128-dot,
        //      direct store, no atomics. q_ reads are wave-uniform (broadcast).
        {
            const int g = t & 255, kq = t >> 8;
            float acc[4][4];   // [r][kk]
#pragma unroll
            for (int r = 0; r < 4; ++r)
#pragma unroll
                for (int kk = 0; kk < 4; ++kk) acc[r][kk] = 0.f;
            for (int c0 = 0; c0 < 128; c0 += 8) {
                bf16x8 kr[4];
#pragma unroll
                for (int r = 0; r < 4; ++r)
                    kr[r] = *(const bf16x8*)&kb[((size_t)b * N_ + g + 256 * r) * D_ + c0];
#pragma unroll
                for (int c4 = 0; c4 < 2; ++c4) {
                    float kf[4][4];
#pragma unroll
                    for (int r = 0; r < 4; ++r)
#pragma unroll
                        for (int j = 0; j < 4; ++j)
                            kf[r][j] = bs2f((ushort_t)kr[r][c4 * 4 + j]);
#pragma unroll
                    for (int kk = 0; kk < 4; ++kk) {
                        f32x4 q4 = *(const f32x4*)&q_[4 * kq + kk][c0 + c4 * 4];
#pragma unroll
                        for (int r = 0; r < 4; ++r) {
                            acc[r][kk] = fmaf(q4[0], kf[r][0], acc[r][kk]);
                            acc[r][kk] = fmaf(q4[1], kf[r][1], acc[r][kk]);
                            acc[r][kk] = fmaf(q4[2], kf[r][2], acc[r][kk]);
                            acc[r][kk] = fmaf(q4[3], kf[r][3], acc[r][kk]);
                        }
                    }
                }
            }
#pragma unroll
            for (int r = 0; r < 4; ++r)
#pragma unroll
                for (int kk = 0; kk < 4; ++kk)
                    attnT[4 * kq + kk][g + 256 * r] = acc[r][kk];
        }
        __syncthreads();

        // ---- softmax over k (per n) + per-wave S partials
        {
            float sloc[8];
#pragma unroll
            for (int k = 0; k < 8; ++k) sloc[k] = 0.f;
#pragma unroll
            for (int half = 0; half < 2; ++half) {
                const int n = t + half * 512;
                float l[8];
#pragma unroll
                for (int k = 0; k < 8; ++k) l[k] = attnT[k][n] * SCALE;
                float mx = l[0];
#pragma unroll
                for (int k = 1; k < 8; ++k) mx = fmaxf(mx, l[k]);
                float e[8], ssum = 0.f;
#pragma unroll
                for (int k = 0; k < 8; ++k) { e[k] = expf(l[k] - mx); ssum += e[k]; }
                float inv = 1.f / ssum;
#pragma unroll
                for (int k = 0; k < 8; ++k) {
                    float p = e[k] * inv;
                    attnT[k][n] = p;
                    sloc[k] += p;
                    if (last) out_attn[((size_t)b * K_ + k) * N_ + n] = p;
                }
            }
#pragma unroll
            for (int k = 0; k < 8; ++k) {
                float v = sloc[k];
                for (int off = 32; off > 0; off >>= 1) v += __shfl_down(v, off, 64);
                if (lane == 0) red2[wv][k] = v;
            }
        }
        __syncthreads();
        if (t < 8) {
            float ss = 0.f;
#pragma unroll
            for (int w = 0; w < 8; ++w) ss += red2[w][t];
            S_[t] = ss;
        }
        // S_ consumed only after the chunk syncs below.

        // ---- C: updates = attn @ v, v staged in LDS chunks of 256 rows.
        //      Thread: d4 = (t&31)*4 (4 d), strip s = t>>5 (16 n per chunk).
        {
            float acc[8][4];
#pragma unroll
            for (int k = 0; k < 8; ++k)
#pragma unroll
                for (int j = 0; j < 4; ++j) acc[k][j] = 0.f;
            const int d4 = (t & 31) * 4, s = t >> 5;
            for (int chunk = 0; chunk < 4; ++chunk) {
                const int n0 = chunk << 8;
                __syncthreads();   // prev chunk consumed before restage
#pragma unroll
                for (int i = 0; i < 8; ++i) {
                    int idx = t + (i << 9);            // 0..4095
                    int row = idx >> 4, u8 = (idx & 15) << 3;
                    *(bf16x8*)&kvt[row * 136 + u8] =
                        *(const bf16x8*)&vb[((size_t)b * N_ + n0 + row) * D_ + u8];
                }
                __syncthreads();
#pragma unroll
                for (int i2 = 0; i2 < 4; ++i2) {
                    const int nn = (s << 4) + (i2 << 2);
                    float vf[4][4];
#pragma unroll
                    for (int i = 0; i < 4; ++i) {
                        ushort4 v4 = *(const ushort4*)&kvt[(nn + i) * 136 + d4];
                        vf[i][0] = bs2f(v4.x); vf[i][1] = bs2f(v4.y);
                        vf[i][2] = bs2f(v4.z); vf[i][3] = bs2f(v4.w);
                    }
#pragma unroll
                    for (int k = 0; k < 8; ++k) {
                        f32x4 a4 = *(const f32x4*)&attnT[k][n0 + nn];
#pragma unroll
                        for (int i = 0; i < 4; ++i) {
                            acc[k][0] = fmaf(a4[i], vf[i][0], acc[k][0]);
                            acc[k][1] = fmaf(a4[i], vf[i][1], acc[k][1]);
                            acc[k][2] = fmaf(a4[i], vf[i][2], acc[k][2]);
                            acc[k][3] = fmaf(a4[i], vf[i][3], acc[k][3]);
                        }
                    }
                }
            }
            __syncthreads();   // compute done; scratch becomes red[]
#pragma unroll
            for (int k = 0; k < 8; ++k)
#pragma unroll
                for (int j = 0; j < 4; ++j)
                    acc[k][j] += __shfl_xor(acc[k][j], 32, 64);
            if (lane < 32) {
#pragma unroll
                for (int k = 0; k < 8; ++k)
#pragma unroll
                    for (int j = 0; j < 4; ++j)
                        red[(wv * 8 + k) * 132 + lane * 4 + j] = acc[k][j];
            }
            __syncthreads();
            for (int i = t; i < 1024; i += 512) {
                int k = i >> 7, d = i & 127;
                float ssum = 0.f;
#pragma unroll
                for (int w = 0; w < 8; ++w) ssum += red[(w * 8 + k) * 132 + d];
                u_[k][d] = ssum / (S_[k] + 1e-8f);
            }
        }
        __syncthreads();

        // ---- D: GRU. Thread: j = t&127, slots kk and kk+4; one weight load
        //      serves both slots. W_ih/W_hh native [384][128] rows (L2-resident).
        {
            const int j = t & 127, kk = t >> 7;
            const int k0 = kk, k1 = kk + 4;
            float ax0 = 0.f, ax1 = 0.f, ax2 = 0.f, ah0 = 0.f, ah1 = 0.f, ah2 = 0.f;
            float bx0 = 0.f, bx1 = 0.f, bx2 = 0.f, bh0 = 0.f, bh1 = 0.f, bh2 = 0.f;
            const float* pih = &W_ih[(size_t)j * 128];
            const float* phh = &W_hh[(size_t)j * 128];
            for (int c0 = 0; c0 < 128; c0 += 4) {
                f32x4 u0 = *(const f32x4*)&u_[k0][c0];
                f32x4 u1 = *(const f32x4*)&u_[k1][c0];
                f32x4 h0 = *(const f32x4*)&sl[k0][c0];
                f32x4 h1 = *(const f32x4*)&sl[k1][c0];
                f32x4 w;
                w = *(const f32x4*)(pih + c0);
                ax0 = fmaf(u0[0], w[0], fmaf(u0[1], w[1], fmaf(u0[2], w[2], fmaf(u0[3], w[3], ax0))));
                bx0 = fmaf(u1[0], w[0], fmaf(u1[1], w[1], fmaf(u1[2], w[2], fmaf(u1[3], w[3], bx0))));
                w = *(const f32x4*)(pih + 16384 + c0);
                ax1 = fmaf(u0[0], w[0], fmaf(u0[1], w[1], fmaf(u0[2], w[2], fmaf(u0[3], w[3], ax1))));
                bx1 = fmaf(u1[0], w[0], fmaf(u1[1], w[1], fmaf(u1[2], w[2], fmaf(u1[3], w[3], bx1))));
                w = *(const f32x4*)(pih + 32768 + c0);
                ax2 = fmaf(u0[0], w[0], fmaf(u0[1], w[1], fmaf(u0[2], w[2], fmaf(u0[3], w[3], ax2))));
                bx2 = fmaf(u1[0], w[0], fmaf(u1[1], w[1], fmaf(u1[2], w[2], fmaf(u1[3], w[3], bx2))));
                w = *(const f32x4*)(phh + c0);
                ah0 = fmaf(h0[0], w[0], fmaf(h0[1], w[1], fmaf(h0[2], w[2], fmaf(h0[3], w[3], ah0))));
                bh0 = fmaf(h1[0], w[0], fmaf(h1[1], w[1], fmaf(h1[2], w[2], fmaf(h1[3], w[3], bh0))));
                w = *(const f32x4*)(phh + 16384 + c0);
                ah1 = fmaf(h0[0], w[0], fmaf(h0[1], w[1], fmaf(h0[2], w[2], fmaf(h0[3], w[3], ah1))));
                bh1 = fmaf(h1[0], w[0], fmaf(h1[1], w[1], fmaf(h1[2], w[2], fmaf(h1[3], w[3], bh1))));
                w = *(const f32x4*)(phh + 32768 + c0);
                ah2 = fmaf(h0[0], w[0], fmaf(h0[1], w[1], fmaf(h0[2], w[2], fmaf(h0[3], w[3], ah2))));
                bh2 = fmaf(h1[0], w[0], fmaf(h1[1], w[1], fmaf(h1[2], w[2], fmaf(h1[3], w[3], bh2))));
            }
            {
                float r = sigmoidf_(ax0 + b_ih[j] + ah0 + b_hh[j]);
                float z = sigmoidf_(ax1 + b_ih[128 + j] + ah1 + b_hh[128 + j]);
                float nv = tanhf(ax2 + b_ih[256 + j] + r * (ah2 + b_hh[256 + j]));
                sn_[k0][j] = (1.f - z) * nv + z * sl[k0][j];
            }
            {
                float r = sigmoidf_(bx0 + b_ih[j] + bh0 + b_hh[j]);
                float z = sigmoidf_(bx1 + b_ih[128 + j] + bh1 + b_hh[128 + j]);
                float nv = tanhf(bx2 + b_ih[256 + j] + r * (bh2 + b_hh[256 + j]));
                sn_[k1][j] = (1.f - z) * nv + z * sl[k1][j];
            }
        }
        __syncthreads();

        // ---- LN(sn_) for MLP
        {
            float v0 = sn_[wv][lane], v1 = sn_[wv][lane + 64];
            float s = v0 + v1, s2 = v0 * v0 + v1 * v1;
            for (int off = 32; off > 0; off >>= 1) {
                s += __shfl_down(s, off, 64);
                s2 += __shfl_down(s2, off, 64);
            }
            if (lane == 0) {
                float mean = s * (1.f / 128.f);
                float var = s2 * (1.f / 128.f) - mean * mean;
                mrs_[wv][0] = mean; mrs_[wv][1] = rsqrtf(var + 1e-5f);
            }
        }
        __syncthreads();
        for (int i = t; i < 1024; i += 512) {
            int k = i >> 7, d = i & 127;
            u_[k][d] = (sn_[k][d] - mrs_[k][0]) * mrs_[k][1] * g_mlp[d] + b_mlp[d];
        }
        __syncthreads();

        // ---- MLP1: hm = gelu(u_ @ W1 + b1). Thread: j = t&127, slots kk, kk+4.
        {
            const int j = t & 127, kk = t >> 7;
            const int k0 = kk, k1 = kk + 4;
            float a00 = 0.f, a01 = 0.f, a10 = 0.f, a11 = 0.f;
            for (int c0 = 0; c0 < 128; c0 += 4) {
                f32x4 t0 = *(const f32x4*)&u_[k0][c0];
                f32x4 t1 = *(const f32x4*)&u_[k1][c0];
#pragma unroll
                for (int e = 0; e < 4; ++e) {
                    float w0 = W1[(size_t)(c0 + e) * 256 + j];
                    float w1 = W1[(size_t)(c0 + e) * 256 + j + 128];
                    a00 = fmaf(t0[e], w0, a00);
                    a01 = fmaf(t0[e], w1, a01);
                    a10 = fmaf(t1[e], w0, a10);
                    a11 = fmaf(t1[e], w1, a11);
                }
            }
            hm_[k0][j] = gelu_exact(a00 + b1[j]);
            hm_[k0][j + 128] = gelu_exact(a01 + b1[j + 128]);
            hm_[k1][j] = gelu_exact(a10 + b1[j]);
            hm_[k1][j + 128] = gelu_exact(a11 + b1[j + 128]);
        }
        __syncthreads();

        // ---- MLP2 + residual: slots = sn_ + hm @ W2 + b2. Thread: d, slots kk, kk+4.
        {
            const int d = t & 127, kk = t >> 7;
            const int k0 = kk, k1 = kk + 4;
            float a0 = sn_[k0][d] + b2[d];
            float a1 = sn_[k1][d] + b2[d];
            for (int j0 = 0; j0 < 256; j0 += 4) {
                f32x4 h0 = *(const f32x4*)&hm_[k0][j0];
                f32x4 h1 = *(const f32x4*)&hm_[k1][j0];
#pragma unroll
                for (int e = 0; e < 4; ++e) {
                    float w = W2[(size_t)(j0 + e) * 128 + d];
                    a0 = fmaf(h0[e], w, a0);
                    a1 = fmaf(h1[e], w, a1);
                }
            }
            sl[k0][d] = a0;
            sl[k1][d] = a1;
            if (last) {
                out_slots[((size_t)b * K_ + k0) * D_ + d] = a0;
                out_slots[((size_t)b * K_ + k1) * D_ + d] = a1;
            }
        }
        __syncthreads();
    }
}

// ---------------------------------------------------------------------------
extern "C" void kernel_launch(void* const* d_in, const int* in_sizes, int n_in,
                              void* d_out, int out_size, void* d_ws, size_t ws_size,
                              hipStream_t stream) {
    const float* x       = (const float*)d_in[0];
    const float* noise   = (const float*)d_in[1];
    const float* slot_mu = (const float*)d_in[2];
    const float* slot_ls = (const float*)d_in[3];
    const float* Wp      = (const float*)d_in[4];
    const float* bp      = (const float*)d_in[5];
    const float* g_in    = (const float*)d_in[6];
    const float* b_in    = (const float*)d_in[7];
    const float* Wq      = (const float*)d_in[8];
    const float* bq      = (const float*)d_in[9];
    const float* Wk      = (const float*)d_in[10];
    const float* bk      = (const float*)d_in[11];
    const float* Wv      = (const float*)d_in[12];
    const float* bv      = (const float*)d_in[13];
    const float* W_ih    = (const float*)d_in[14];
    const float* W_hh    = (const float*)d_in[15];
    const float* b_ih    = (const float*)d_in[16];
    const float* b_hh    = (const float*)d_in[17];
    const float* W1      = (const float*)d_in[18];
    const float* b1      = (const float*)d_in[19];
    const float* W2      = (const float*)d_in[20];
    const float* b2      = (const float*)d_in[21];
    const float* g_slots = (const float*)d_in[22];
    const float* b_slots = (const float*)d_in[23];
    const float* g_mlp   = (const float*)d_in[24];
    const float* b_mlp   = (const float*)d_in[25];

    float* out_slots = (float*)d_out;            // [64,8,128] fp32
    float* out_attn  = (float*)d_out + 65536;    // [64,8,1024] fp32

    // workspace layout (float units) — unchanged offsets
    float* wsf = (float*)d_ws;
    ushort_t* inputsb = (ushort_t*)wsf;                    // 65536x128 bf16
    ushort_t* kb = (ushort_t*)(wsf + 4194304);             // 65536x128 bf16
    ushort_t* vb = (ushort_t*)(wsf + 8388608);             // 65536x128 bf16
    ushort_t* WpT = (ushort_t*)(wsf + 13304320);  // 128x512 bf16
    ushort_t* WkT = (ushort_t*)(wsf + 13337088);  // 128x128 bf16
    ushort_t* WvT = (ushort_t*)(wsf + 13345280);  // 128x128 bf16
    float* WTih = wsf + 13353472;    // 128x384 fp32 (unused by fused kernel)
    float* WThh = wsf + 13402624;    // 128x384 fp32 (unused by fused kernel)

    prep_weights<<<dim3(256), dim3(256), 0, stream>>>(
        Wp, Wk, Wv, W_ih, W_hh, WpT, WkT, WvT, WTih, WThh);
    proj_ln_mfma<<<dim3(1024), dim3(256), 0, stream>>>(x, WpT, bp, g_in, b_in, inputsb);
    kv_mfma<<<dim3(1024), dim3(256), 0, stream>>>(inputsb, WkT, bk, WvT, bv, kb, vb);

    fused_slots<<<dim3(64), dim3(512), 0, stream>>>(
        kb, vb, noise, slot_mu, slot_ls, g_slots, b_slots, Wq, bq,
        W_ih, W_hh, b_ih, b_hh, W1, b1, W2, b2, g_mlp, b_mlp,
        out_slots, out_attn);
}

// Round 4
// 1052.395 us; speedup vs baseline: 2.2398x; 1.1485x over previous
//
#include <hip/hip_runtime.h>
#include <hip/hip_bf16.h>
#include <math.h>

#define B_ 64
#define C_ 512
#define N_ 1024
#define D_ 128
#define K_ 8

typedef __attribute__((ext_vector_type(8))) short bf16x8;  // 8 bf16 = 4 VGPRs
typedef __attribute__((ext_vector_type(4))) float f32x4;
typedef unsigned short ushort_t;

__device__ __forceinline__ unsigned short f2bs(float f) {
    union { __hip_bfloat16 h; unsigned short s; } u;
    u.h = __float2bfloat16(f);
    return u.s;
}
__device__ __forceinline__ float bs2f(unsigned short s) {
    union { unsigned int u; float f; } v;
    v.u = ((unsigned int)s) << 16;
    return v.f;
}
__device__ __forceinline__ float sigmoidf_(float x) { return 1.0f / (1.0f + expf(-x)); }
__device__ __forceinline__ float gelu_exact(float x) {
    return 0.5f * x * (1.0f + erff(x * 0.7071067811865476f));
}

// ---------------------------------------------------------------------------
// K0: weight prep (unchanged, proven). WTih/WThh used again by fused GRU.
// ---------------------------------------------------------------------------
__global__ __launch_bounds__(256) void prep_weights(
    const float* __restrict__ Wp, const float* __restrict__ Wk,
    const float* __restrict__ Wv, const float* __restrict__ W_ih,
    const float* __restrict__ W_hh,
    ushort_t* __restrict__ WpT, ushort_t* __restrict__ WkT,
    ushort_t* __restrict__ WvT, float* __restrict__ WTih,
    float* __restrict__ WThh)
{
    int tid = blockIdx.x * 256 + threadIdx.x;   // grid 256*256 = 65536
    {
        int c = tid >> 7, d = tid & 127;        // coalesced read of Wp
        WpT[d * 512 + c] = f2bs(Wp[tid]);
    }
    if (tid < 16384) {
        int c = tid >> 7, d = tid & 127;
        WkT[d * 128 + c] = f2bs(Wk[tid]);
        WvT[d * 128 + c] = f2bs(Wv[tid]);
    }
    if (tid < 49152) {
        int j = tid >> 7, c = tid & 127;        // coalesced read of W_ih
        WTih[c * 384 + j] = W_ih[tid];
        WThh[c * 384 + j] = W_hh[tid];
    }
}

// ---------------------------------------------------------------------------
// K1: inputs = LN(x_flat @ Wp + bp)*g+b via MFMA bf16 (unchanged, proven).
// ---------------------------------------------------------------------------
__global__ __launch_bounds__(256) void proj_ln_mfma(
    const float* __restrict__ x, const ushort_t* __restrict__ WpT,
    const float* __restrict__ bp, const float* __restrict__ g_in,
    const float* __restrict__ b_in, ushort_t* __restrict__ outb)
{
    __shared__ ushort_t Al[64 * 40];
    __shared__ ushort_t Bl[128 * 40];
    __shared__ float red[64][2][2];
    const int t = threadIdx.x;
    const int b = blockIdx.x >> 4;
    const int n0 = (blockIdx.x & 15) << 6;
    const int w = t >> 6, lane = t & 63;
    const int quad = lane >> 4, m = lane & 15;
    const int rowoff = (w >> 1) << 5;   // 0 / 32
    const int coloff = (w & 1) << 6;    // 0 / 64

    f32x4 acc[2][4];
#pragma unroll
    for (int r = 0; r < 2; ++r)
#pragma unroll
        for (int c = 0; c < 4; ++c) acc[r][c] = (f32x4){0.f, 0.f, 0.f, 0.f};

    const float* xb = x + (size_t)b * (C_ * N_);
    for (int c0 = 0; c0 < C_; c0 += 32) {
#pragma unroll
        for (int i = 0; i < 8; ++i) {
            int idx = t + (i << 8);
            int cc = idx >> 6, nn = idx & 63;
            Al[nn * 40 + cc] = f2bs(xb[(size_t)(c0 + cc) * N_ + n0 + nn]);
        }
#pragma unroll
        for (int i = 0; i < 2; ++i) {
            int idx = t + (i << 8);           // 0..511
            int d = idx >> 2, seg = idx & 3;  // 128 rows x 4 segs of 8
            *(bf16x8*)&Bl[d * 40 + seg * 8] =
                *(const bf16x8*)&WpT[d * 512 + c0 + seg * 8];
        }
        __syncthreads();
        bf16x8 af[2], bfr[4];
#pragma unroll
        for (int r = 0; r < 2; ++r)
            af[r] = *(const bf16x8*)&Al[(rowoff + 16 * r + m) * 40 + quad * 8];
#pragma unroll
        for (int c = 0; c < 4; ++c)
            bfr[c] = *(const bf16x8*)&Bl[(coloff + 16 * c + m) * 40 + quad * 8];
#pragma unroll
        for (int r = 0; r < 2; ++r)
#pragma unroll
            for (int c = 0; c < 4; ++c)
                acc[r][c] = __builtin_amdgcn_mfma_f32_16x16x32_bf16(af[r], bfr[c], acc[r][c], 0, 0, 0);
        __syncthreads();
    }
    float gv[4], bv[4], bpv[4];
#pragma unroll
    for (int c = 0; c < 4; ++c) {
        int col = coloff + 16 * c + m;
        bpv[c] = bp[col]; gv[c] = g_in[col]; bv[c] = b_in[col];
    }
#pragma unroll
    for (int r = 0; r < 2; ++r)
#pragma unroll
        for (int c = 0; c < 4; ++c)
#pragma unroll
            for (int g = 0; g < 4; ++g) acc[r][c][g] += bpv[c];

#pragma unroll
    for (int r = 0; r < 2; ++r) {
#pragma unroll
        for (int g = 0; g < 4; ++g) {
            float s = 0.f, s2 = 0.f;
#pragma unroll
            for (int c = 0; c < 4; ++c) { float v = acc[r][c][g]; s += v; s2 += v * v; }
#pragma unroll
            for (int off = 1; off < 16; off <<= 1) {
                s += __shfl_xor(s, off, 64);
                s2 += __shfl_xor(s2, off, 64);
            }
            if (m == 0) {
                int row = rowoff + 16 * r + quad * 4 + g;
                red[row][w & 1][0] = s;
                red[row][w & 1][1] = s2;
            }
        }
    }
    __syncthreads();
#pragma unroll
    for (int r = 0; r < 2; ++r) {
#pragma unroll
        for (int g = 0; g < 4; ++g) {
            int row = rowoff + 16 * r + quad * 4 + g;
            float s = red[row][0][0] + red[row][1][0];
            float s2 = red[row][0][1] + red[row][1][1];
            float mean = s * (1.f / 128.f);
            float var = s2 * (1.f / 128.f) - mean * mean;
            float rs = rsqrtf(var + 1e-5f);
            size_t base = ((size_t)b * N_ + n0 + row) * D_;
#pragma unroll
            for (int c = 0; c < 4; ++c) {
                int col = coloff + 16 * c + m;
                float v = (acc[r][c][g] - mean) * rs * gv[c] + bv[c];
                outb[base + col] = f2bs(v);
            }
        }
    }
}

// ---------------------------------------------------------------------------
// K2: k/v = A@Wk/Wv + bias (unchanged, proven).
// ---------------------------------------------------------------------------
__global__ __launch_bounds__(256) void kv_mfma(
    const ushort_t* __restrict__ A,
    const ushort_t* __restrict__ WkT, const float* __restrict__ bk,
    const ushort_t* __restrict__ WvT, const float* __restrict__ bv,
    ushort_t* __restrict__ kout, ushort_t* __restrict__ vout)
{
    __shared__ ushort_t Al[64 * 40];
    __shared__ ushort_t Bk[128 * 40];
    __shared__ ushort_t Bv[128 * 40];
    const int t = threadIdx.x;
    const int row0 = blockIdx.x << 6;
    const int w = t >> 6, lane = t & 63;
    const int quad = lane >> 4, m = lane & 15;
    const int is_v = w >> 1;
    const int rowoff = (w & 1) << 5;

    f32x4 acc[2][8];
#pragma unroll
    for (int r = 0; r < 2; ++r)
#pragma unroll
        for (int c = 0; c < 8; ++c) acc[r][c] = (f32x4){0.f, 0.f, 0.f, 0.f};

    for (int c0 = 0; c0 < D_; c0 += 32) {
#pragma unroll
        for (int i = 0; i < 2; ++i) {
            int idx = t + (i << 8);
            int rr = idx >> 3, cc4 = (idx & 7) << 2;
            *(ushort4*)&Al[rr * 40 + cc4] =
                *(const ushort4*)&A[(size_t)(row0 + rr) * D_ + c0 + cc4];
        }
#pragma unroll
        for (int i = 0; i < 2; ++i) {
            int idx = t + (i << 8);
            int d = idx >> 2, seg = idx & 3;
            *(bf16x8*)&Bk[d * 40 + seg * 8] =
                *(const bf16x8*)&WkT[d * 128 + c0 + seg * 8];
            *(bf16x8*)&Bv[d * 40 + seg * 8] =
                *(const bf16x8*)&WvT[d * 128 + c0 + seg * 8];
        }
        __syncthreads();
        const ushort_t* Bsrc = is_v ? Bv : Bk;
        bf16x8 af[2], bfr[8];
#pragma unroll
        for (int r = 0; r < 2; ++r)
            af[r] = *(const bf16x8*)&Al[(rowoff + 16 * r + m) * 40 + quad * 8];
#pragma unroll
        for (int c = 0; c < 8; ++c)
            bfr[c] = *(const bf16x8*)&Bsrc[(16 * c + m) * 40 + quad * 8];
#pragma unroll
        for (int r = 0; r < 2; ++r)
#pragma unroll
            for (int c = 0; c < 8; ++c)
                acc[r][c] = __builtin_amdgcn_mfma_f32_16x16x32_bf16(af[r], bfr[c], acc[r][c], 0, 0, 0);
        __syncthreads();
    }
    const float* bias = is_v ? bv : bk;
    ushort_t* dst = is_v ? vout : kout;
    float bval[8];
#pragma unroll
    for (int c = 0; c < 8; ++c) bval[c] = bias[16 * c + m];
#pragma unroll
    for (int r = 0; r < 2; ++r) {
#pragma unroll
        for (int g = 0; g < 4; ++g) {
            int row = rowoff + 16 * r + quad * 4 + g;
            size_t base = (size_t)(row0 + row) * D_;
#pragma unroll
            for (int c = 0; c < 8; ++c)
                dst[base + 16 * c + m] = f2bs(acc[r][c][g] + bval[c]);
        }
    }
}

// ---------------------------------------------------------------------------
// K3: fused slot loop, v3. 64 blocks x 512 threads (8 waves), lb(512,2).
// v2 failure (957us, VALUBusy 2%): phases B and D used per-lane-ROW global
// reads (64 lines per load instr, 8x over-fetch, latency-bound at 2 waves/
// SIMD). v3 restores the proven-coalesced patterns inside the fusion:
//   B: kb staged to LDS via the same bf16x8 copy as phase C (coalesced),
//      compute from LDS (per-lane-row ds_read_b128 at pitch 136 = 8-cycle
//      minimum, q reads wave-uniform broadcast).
//   D: GRU via pre-transposed WTih/WThh (lane = gate j -> coalesced),
//      8 slot-rows register-blocked per thread; gates parked in scratch LDS.
// ---------------------------------------------------------------------------
__global__ __launch_bounds__(512, 2) void fused_slots(
    const ushort_t* __restrict__ kb, const ushort_t* __restrict__ vb,
    const float* __restrict__ noise, const float* __restrict__ mu,
    const float* __restrict__ lsig,
    const float* __restrict__ g_slots, const float* __restrict__ b_slots,
    const float* __restrict__ Wq, const float* __restrict__ bq,
    const float* __restrict__ WTih, const float* __restrict__ WThh,
    const float* __restrict__ b_ih, const float* __restrict__ b_hh,
    const float* __restrict__ W1, const float* __restrict__ b1,
    const float* __restrict__ W2, const float* __restrict__ b2,
    const float* __restrict__ g_mlp, const float* __restrict__ b_mlp,
    float* __restrict__ out_slots, float* __restrict__ out_attn)
{
    __shared__ __align__(16) float sl[8][132];      // slots
    __shared__ __align__(16) float u_[8][132];      // ln(slots) -> upd -> ln_mlp temp
    __shared__ __align__(16) float sn_[8][132];     // GRU output
    __shared__ __align__(16) float q_[8][132];
    __shared__ __align__(16) float attnT[8][1032];  // logits -> softmax attn
    __shared__ __align__(16) char scratch[69632];   // kvt[256][136] bf16 U red U gxb/ghb
    __shared__ __align__(16) float hm_[8][260];     // MLP hidden
    __shared__ float red2[8][8];      // per-wave S partials
    __shared__ float S_[8];
    __shared__ float mrs_[8][2];

    ushort_t* kvt = (ushort_t*)scratch;
    float* red = (float*)scratch;
    float* gxb = (float*)scratch;            // [8][384] GRU input-gates
    float* ghb = (float*)scratch + 3072;     // [8][384] GRU hidden-gates

    const int t = threadIdx.x;
    const int b = blockIdx.x;
    const int wv = t >> 6, lane = t & 63;
    const float SCALE = 0.08838834764831845f;

    // slots init
    for (int i = t; i < 1024; i += 512) {
        sl[i >> 7][i & 127] = mu[i] + expf(lsig[i]) * noise[b * 1024 + i];
    }
    __syncthreads();

    for (int it = 0; it < 3; ++it) {
        const int last = (it == 2);

        // ---- A1: LN stats over slots: wave wv handles slot-row wv
        {
            float v0 = sl[wv][lane], v1 = sl[wv][lane + 64];
            float s = v0 + v1, s2 = v0 * v0 + v1 * v1;
            for (int off = 32; off > 0; off >>= 1) {
                s += __shfl_down(s, off, 64);
                s2 += __shfl_down(s2, off, 64);
            }
            if (lane == 0) {
                float mean = s * (1.f / 128.f);
                float var = s2 * (1.f / 128.f) - mean * mean;
                mrs_[wv][0] = mean; mrs_[wv][1] = rsqrtf(var + 1e-5f);
            }
        }
        __syncthreads();

        // ---- A2: u_ = LN(slots)*g+b
        for (int i = t; i < 1024; i += 512) {
            int k = i >> 7, d = i & 127;
            u_[k][d] = (sl[k][d] - mrs_[k][0]) * mrs_[k][1] * g_slots[d] + b_slots[d];
        }
        __syncthreads();

        // ---- A3: q = u_ @ Wq + bq  (coalesced Wq column reads; one weight
        //      load serves slots kk and kk+4)
        {
            const int d = t & 127, kk = t >> 7;
            float a0 = bq[d], a1 = bq[d];
            for (int c0 = 0; c0 < 128; c0 += 4) {
                f32x4 u0 = *(const f32x4*)&u_[kk][c0];
                f32x4 u1 = *(const f32x4*)&u_[kk + 4][c0];
#pragma unroll
                for (int e = 0; e < 4; ++e) {
                    float w = Wq[(size_t)(c0 + e) * 128 + d];
                    a0 = fmaf(u0[e], w, a0);
                    a1 = fmaf(u1[e], w, a1);
                }
            }
            q_[kk][d] = a0;
            q_[kk + 4][d] = a1;
        }
        __syncthreads();

        // ---- B: logits via LDS-staged kb (4 chunks x 256 rows).
        //      Thread (row = t&255, kq = t>>8) computes 4 k-dots for its row.
        {
            const int row = t & 255, kq = t >> 8;
            for (int chunk = 0; chunk < 4; ++chunk) {
                const int n0 = chunk << 8;
                __syncthreads();   // previous chunk's compute done
#pragma unroll
                for (int i = 0; i < 8; ++i) {
                    int idx = t + (i << 9);            // 0..4095
                    int rr = idx >> 4, u8 = (idx & 15) << 3;
                    *(bf16x8*)&kvt[rr * 136 + u8] =
                        *(const bf16x8*)&kb[((size_t)b * N_ + n0 + rr) * D_ + u8];
                }
                __syncthreads();
                float acc[4];
#pragma unroll
                for (int kk = 0; kk < 4; ++kk) acc[kk] = 0.f;
                for (int c0 = 0; c0 < 128; c0 += 8) {
                    bf16x8 kr = *(const bf16x8*)&kvt[row * 136 + c0];
                    float kf[8];
#pragma unroll
                    for (int j = 0; j < 8; ++j) kf[j] = bs2f((ushort_t)kr[j]);
#pragma unroll
                    for (int kk = 0; kk < 4; ++kk) {
                        f32x4 qa = *(const f32x4*)&q_[4 * kq + kk][c0];
                        f32x4 qb = *(const f32x4*)&q_[4 * kq + kk][c0 + 4];
                        acc[kk] = fmaf(qa[0], kf[0], acc[kk]);
                        acc[kk] = fmaf(qa[1], kf[1], acc[kk]);
                        acc[kk] = fmaf(qa[2], kf[2], acc[kk]);
                        acc[kk] = fmaf(qa[3], kf[3], acc[kk]);
                        acc[kk] = fmaf(qb[0], kf[4], acc[kk]);
                        acc[kk] = fmaf(qb[1], kf[5], acc[kk]);
                        acc[kk] = fmaf(qb[2], kf[6], acc[kk]);
                        acc[kk] = fmaf(qb[3], kf[7], acc[kk]);
                    }
                }
#pragma unroll
                for (int kk = 0; kk < 4; ++kk)
                    attnT[4 * kq + kk][n0 + row] = acc[kk];
            }
        }
        __syncthreads();

        // ---- softmax over k (per n) + per-wave S partials
        {
            float sloc[8];
#pragma unroll
            for (int k = 0; k < 8; ++k) sloc[k] = 0.f;
#pragma unroll
            for (int half = 0; half < 2; ++half) {
                const int n = t + half * 512;
                float l[8];
#pragma unroll
                for (int k = 0; k < 8; ++k) l[k] = attnT[k][n] * SCALE;
                float mx = l[0];
#pragma unroll
                for (int k = 1; k < 8; ++k) mx = fmaxf(mx, l[k]);
                float e[8], ssum = 0.f;
#pragma unroll
                for (int k = 0; k < 8; ++k) { e[k] = expf(l[k] - mx); ssum += e[k]; }
                float inv = 1.f / ssum;
#pragma unroll
                for (int k = 0; k < 8; ++k) {
                    float p = e[k] * inv;
                    attnT[k][n] = p;
                    sloc[k] += p;
                    if (last) out_attn[((size_t)b * K_ + k) * N_ + n] = p;
                }
            }
#pragma unroll
            for (int k = 0; k < 8; ++k) {
                float v = sloc[k];
                for (int off = 32; off > 0; off >>= 1) v += __shfl_down(v, off, 64);
                if (lane == 0) red2[wv][k] = v;
            }
        }
        __syncthreads();
        if (t < 8) {
            float ss = 0.f;
#pragma unroll
            for (int w = 0; w < 8; ++w) ss += red2[w][t];
            S_[t] = ss;
        }
        // S_ consumed only after the chunk syncs below.

        // ---- C: updates = attn @ v, v staged in LDS chunks of 256 rows
        //      (unchanged, proven coalesced + conflict-free).
        {
            float acc[8][4];
#pragma unroll
            for (int k = 0; k < 8; ++k)
#pragma unroll
                for (int j = 0; j < 4; ++j) acc[k][j] = 0.f;
            const int d4 = (t & 31) * 4, s = t >> 5;
            for (int chunk = 0; chunk < 4; ++chunk) {
                const int n0 = chunk << 8;
                __syncthreads();   // prev chunk consumed before restage
#pragma unroll
                for (int i = 0; i < 8; ++i) {
                    int idx = t + (i << 9);            // 0..4095
                    int row = idx >> 4, u8 = (idx & 15) << 3;
                    *(bf16x8*)&kvt[row * 136 + u8] =
                        *(const bf16x8*)&vb[((size_t)b * N_ + n0 + row) * D_ + u8];
                }
                __syncthreads();
#pragma unroll
                for (int i2 = 0; i2 < 4; ++i2) {
                    const int nn = (s << 4) + (i2 << 2);
                    float vf[4][4];
#pragma unroll
                    for (int i = 0; i < 4; ++i) {
                        ushort4 v4 = *(const ushort4*)&kvt[(nn + i) * 136 + d4];
                        vf[i][0] = bs2f(v4.x); vf[i][1] = bs2f(v4.y);
                        vf[i][2] = bs2f(v4.z); vf[i][3] = bs2f(v4.w);
                    }
#pragma unroll
                    for (int k = 0; k < 8; ++k) {
                        f32x4 a4 = *(const f32x4*)&attnT[k][n0 + nn];
#pragma unroll
                        for (int i = 0; i < 4; ++i) {
                            acc[k][0] = fmaf(a4[i], vf[i][0], acc[k][0]);
                            acc[k][1] = fmaf(a4[i], vf[i][1], acc[k][1]);
                            acc[k][2] = fmaf(a4[i], vf[i][2], acc[k][2]);
                            acc[k][3] = fmaf(a4[i], vf[i][3], acc[k][3]);
                        }
                    }
                }
            }
            __syncthreads();   // compute done; scratch becomes red[]
#pragma unroll
            for (int k = 0; k < 8; ++k)
#pragma unroll
                for (int j = 0; j < 4; ++j)
                    acc[k][j] += __shfl_xor(acc[k][j], 32, 64);
            if (lane < 32) {
#pragma unroll
                for (int k = 0; k < 8; ++k)
#pragma unroll
                    for (int j = 0; j < 4; ++j)
                        red[(wv * 8 + k) * 132 + lane * 4 + j] = acc[k][j];
            }
            __syncthreads();
            for (int i = t; i < 1024; i += 512) {
                int k = i >> 7, d = i & 127;
                float ssum = 0.f;
#pragma unroll
                for (int w = 0; w < 8; ++w) ssum += red[(w * 8 + k) * 132 + d];
                u_[k][d] = ssum / (S_[k] + 1e-8f);
            }
        }
        __syncthreads();

        // ---- D: GRU part 1 — gates via pre-transposed WTih/WThh (coalesced:
        //      lane = j). Thread j accumulates all 8 slot-rows (one weight
        //      load serves 8 rows). Waves 6,7 idle (wave-uniform skip).
        if (t < 384) {
            const int j = t;
            float accx[8], acch[8];
#pragma unroll
            for (int r = 0; r < 8; ++r) { accx[r] = 0.f; acch[r] = 0.f; }
            for (int c0 = 0; c0 < 128; c0 += 4) {
                float wx[4], wh[4];
#pragma unroll
                for (int e = 0; e < 4; ++e) {
                    wx[e] = WTih[(size_t)(c0 + e) * 384 + j];
                    wh[e] = WThh[(size_t)(c0 + e) * 384 + j];
                }
#pragma unroll
                for (int r = 0; r < 8; ++r) {
                    f32x4 u4 = *(const f32x4*)&u_[r][c0];
                    f32x4 h4 = *(const f32x4*)&sl[r][c0];
#pragma unroll
                    for (int e = 0; e < 4; ++e) {
                        accx[r] = fmaf(u4[e], wx[e], accx[r]);
                        acch[r] = fmaf(h4[e], wh[e], acch[r]);
                    }
                }
            }
            float bx = b_ih[j], bh = b_hh[j];
#pragma unroll
            for (int r = 0; r < 8; ++r) {
                gxb[r * 384 + j] = accx[r] + bx;
                ghb[r * 384 + j] = acch[r] + bh;
            }
        }
        __syncthreads();

        // ---- D: GRU part 2 — combine gates (PyTorch order r,z,n)
#pragma unroll
        for (int e = 0; e < 2; ++e) {
            int idx = t + (e << 9);       // 0..1023
            int row = idx >> 7, d = idx & 127;
            float r = sigmoidf_(gxb[row * 384 + d] + ghb[row * 384 + d]);
            float z = sigmoidf_(gxb[row * 384 + 128 + d] + ghb[row * 384 + 128 + d]);
            float nv = tanhf(gxb[row * 384 + 256 + d] + r * ghb[row * 384 + 256 + d]);
            sn_[row][d] = (1.f - z) * nv + z * sl[row][d];
        }
        __syncthreads();

        // ---- LN(sn_) for MLP
        {
            float v0 = sn_[wv][lane], v1 = sn_[wv][lane + 64];
            float s = v0 + v1, s2 = v0 * v0 + v1 * v1;
            for (int off = 32; off > 0; off >>= 1) {
                s += __shfl_down(s, off, 64);
                s2 += __shfl_down(s2, off, 64);
            }
            if (lane == 0) {
                float mean = s * (1.f / 128.f);
                float var = s2 * (1.f / 128.f) - mean * mean;
                mrs_[wv][0] = mean; mrs_[wv][1] = rsqrtf(var + 1e-5f);
            }
        }
        __syncthreads();
        for (int i = t; i < 1024; i += 512) {
            int k = i >> 7, d = i & 127;
            u_[k][d] = (sn_[k][d] - mrs_[k][0]) * mrs_[k][1] * g_mlp[d] + b_mlp[d];
        }
        __syncthreads();

        // ---- MLP1: hm = gelu(u_ @ W1 + b1). Coalesced W1 column reads.
        {
            const int j = t & 127, kk = t >> 7;
            const int k0 = kk, k1 = kk + 4;
            float a00 = 0.f, a01 = 0.f, a10 = 0.f, a11 = 0.f;
            for (int c0 = 0; c0 < 128; c0 += 4) {
                f32x4 t0 = *(const f32x4*)&u_[k0][c0];
                f32x4 t1 = *(const f32x4*)&u_[k1][c0];
#pragma unroll
                for (int e = 0; e < 4; ++e) {
                    float w0 = W1[(size_t)(c0 + e) * 256 + j];
                    float w1 = W1[(size_t)(c0 + e) * 256 + j + 128];
                    a00 = fmaf(t0[e], w0, a00);
                    a01 = fmaf(t0[e], w1, a01);
                    a10 = fmaf(t1[e], w0, a10);
                    a11 = fmaf(t1[e], w1, a11);
                }
            }
            hm_[k0][j] = gelu_exact(a00 + b1[j]);
            hm_[k0][j + 128] = gelu_exact(a01 + b1[j + 128]);
            hm_[k1][j] = gelu_exact(a10 + b1[j]);
            hm_[k1][j + 128] = gelu_exact(a11 + b1[j + 128]);
        }
        __syncthreads();

        // ---- MLP2 + residual: slots = sn_ + hm @ W2 + b2. Coalesced W2 reads.
        {
            const int d = t & 127, kk = t >> 7;
            const int k0 = kk, k1 = kk + 4;
            float a0 = sn_[k0][d] + b2[d];
            float a1 = sn_[k1][d] + b2[d];
            for (int j0 = 0; j0 < 256; j0 += 4) {
                f32x4 h0 = *(const f32x4*)&hm_[k0][j0];
                f32x4 h1 = *(const f32x4*)&hm_[k1][j0];
#pragma unroll
                for (int e = 0; e < 4; ++e) {
                    float w = W2[(size_t)(j0 + e) * 128 + d];
                    a0 = fmaf(h0[e], w, a0);
                    a1 = fmaf(h1[e], w, a1);
                }
            }
            sl[k0][d] = a0;
            sl[k1][d] = a1;
            if (last) {
                out_slots[((size_t)b * K_ + k0) * D_ + d] = a0;
                out_slots[((size_t)b * K_ + k1) * D_ + d] = a1;
            }
        }
        __syncthreads();
    }
}

// ---------------------------------------------------------------------------
extern "C" void kernel_launch(void* const* d_in, const int* in_sizes, int n_in,
                              void* d_out, int out_size, void* d_ws, size_t ws_size,
                              hipStream_t stream) {
    const float* x       = (const float*)d_in[0];
    const float* noise   = (const float*)d_in[1];
    const float* slot_mu = (const float*)d_in[2];
    const float* slot_ls = (const float*)d_in[3];
    const float* Wp      = (const float*)d_in[4];
    const float* bp      = (const float*)d_in[5];
    const float* g_in    = (const float*)d_in[6];
    const float* b_in    = (const float*)d_in[7];
    const float* Wq      = (const float*)d_in[8];
    const float* bq      = (const float*)d_in[9];
    const float* Wk      = (const float*)d_in[10];
    const float* bk      = (const float*)d_in[11];
    const float* Wv      = (const float*)d_in[12];
    const float* bv      = (const float*)d_in[13];
    const float* W_ih    = (const float*)d_in[14];
    const float* W_hh    = (const float*)d_in[15];
    const float* b_ih    = (const float*)d_in[16];
    const float* b_hh    = (const float*)d_in[17];
    const float* W1      = (const float*)d_in[18];
    const float* b1      = (const float*)d_in[19];
    const float* W2      = (const float*)d_in[20];
    const float* b2      = (const float*)d_in[21];
    const float* g_slots = (const float*)d_in[22];
    const float* b_slots = (const float*)d_in[23];
    const float* g_mlp   = (const float*)d_in[24];
    const float* b_mlp   = (const float*)d_in[25];

    float* out_slots = (float*)d_out;            // [64,8,128] fp32
    float* out_attn  = (float*)d_out + 65536;    // [64,8,1024] fp32

    // workspace layout (float units) — unchanged offsets
    float* wsf = (float*)d_ws;
    ushort_t* inputsb = (ushort_t*)wsf;                    // 65536x128 bf16
    ushort_t* kb = (ushort_t*)(wsf + 4194304);             // 65536x128 bf16
    ushort_t* vb = (ushort_t*)(wsf + 8388608);             // 65536x128 bf16
    ushort_t* WpT = (ushort_t*)(wsf + 13304320);  // 128x512 bf16
    ushort_t* WkT = (ushort_t*)(wsf + 13337088);  // 128x128 bf16
    ushort_t* WvT = (ushort_t*)(wsf + 13345280);  // 128x128 bf16
    float* WTih = wsf + 13353472;    // 128x384 fp32
    float* WThh = wsf + 13402624;    // 128x384 fp32

    prep_weights<<<dim3(256), dim3(256), 0, stream>>>(
        Wp, Wk, Wv, W_ih, W_hh, WpT, WkT, WvT, WTih, WThh);
    proj_ln_mfma<<<dim3(1024), dim3(256), 0, stream>>>(x, WpT, bp, g_in, b_in, inputsb);
    kv_mfma<<<dim3(1024), dim3(256), 0, stream>>>(inputsb, WkT, bk, WvT, bv, kb, vb);

    fused_slots<<<dim3(64), dim3(512), 0, stream>>>(
        kb, vb, noise, slot_mu, slot_ls, g_slots, b_slots, Wq, bq,
        WTih, WThh, b_ih, b_hh, W1, b1, W2, b2, g_mlp, b_mlp,
        out_slots, out_attn);
}